// Round 5
// baseline (250.628 us; speedup 1.0000x reference)
//
#include <hip/hip_runtime.h>
#include <hip/hip_bf16.h>

typedef __hip_bfloat16 bf16;
typedef short bf16x8 __attribute__((ext_vector_type(8)));
typedef short short4v __attribute__((ext_vector_type(4)));
typedef float f32x4 __attribute__((ext_vector_type(4)));

#define B_ 2
#define T_ 2048
#define C_ 768
#define H_ 12
#define HS_ 64
#define M_ (B_ * T_)              // 4096
#define XN_ (B_ * T_ * C_)        // 3145728
#define WN_ (C_ * C_)             // 589824
#define SCALE_ 0.036084391824351615f  // 1/sqrt(768)

__device__ inline short bf16bits(float f) {
    union { bf16 b; short s; } u; u.b = __float2bfloat16(f); return u.s;
}

__device__ inline void load_lds16(const void* g, void* l) {
    __builtin_amdgcn_global_load_lds(
        (const __attribute__((address_space(1))) unsigned int*)g,
        (__attribute__((address_space(3))) unsigned int*)l, 16, 0, 0);
}

// fp32 -> bf16 for x, w_u, w_v, w_p in one pass (4 elems/thread)
__global__ __launch_bounds__(256) void cvt_all(
    const float* __restrict__ x,  const float* __restrict__ wu,
    const float* __restrict__ wv, const float* __restrict__ wp,
    bf16* __restrict__ Xb,  bf16* __restrict__ Wub,
    bf16* __restrict__ Wvb, bf16* __restrict__ Wpb)
{
    const long e = (long)(blockIdx.x * 256 + threadIdx.x) * 4;
    const float* src; bf16* dst; long off;
    if (e < XN_)                { src = x;  dst = Xb;  off = e; }
    else if (e < XN_ + WN_)     { src = wu; dst = Wub; off = e - XN_; }
    else if (e < XN_ + 2*WN_)   { src = wv; dst = Wvb; off = e - XN_ - WN_; }
    else                        { src = wp; dst = Wpb; off = e - XN_ - 2L*WN_; }
    f32x4 v = *(const f32x4*)(src + off);
    short4v o;
#pragma unroll
    for (int i = 0; i < 4; ++i) o[i] = bf16bits(v[i]);
    *(short4v*)(dst + off) = o;
}

// Y[m][n] = (sum_k A[m][k] * W[n][k] + bias[n]) * oscale   (bf16 in, LDS-staged)
// Block: 64x64 output tile, 4 waves, K-step 128 (4 x 32-wide subtiles).
// VT=1: scatter output to Vt[b][h][d][t] (bf16) for the attention PV pass.
template<typename TOUT, int VT>
__global__ __launch_bounds__(256) void gemm_lds(
    const bf16* __restrict__ A, const bf16* __restrict__ Wb,
    const float* __restrict__ bias, TOUT* __restrict__ Y,
    int M, int N, int K, float oscale)
{
    __shared__ __align__(16) short tA[4][64][32];
    __shared__ __align__(16) short tB[4][64][32];

    const int tid  = threadIdx.x;
    const int wave = tid >> 6, lane = tid & 63;
    const int nl = lane & 15, quad = lane >> 4, kq = quad * 8;
    const int m0 = blockIdx.x * 64, n0 = blockIdx.y * 64;

    const int lrow = tid >> 2, lkc = tid & 3;   // staging: row, 8-elem k-chunk
    const bf16* ga = A  + (size_t)(m0 + lrow) * K + lkc * 8;
    const bf16* gb = Wb + (size_t)(n0 + lrow) * K + lkc * 8;
    char* ldsA = (char*)&tA[0][0][0] + wave * 1024;   // lane scatter = lane*16
    char* ldsB = (char*)&tB[0][0][0] + wave * 1024;

    f32x4 acc[4] = {f32x4{0,0,0,0}, f32x4{0,0,0,0}, f32x4{0,0,0,0}, f32x4{0,0,0,0}};

    for (int k0 = 0; k0 < K; k0 += 128) {
#pragma unroll
        for (int j = 0; j < 4; ++j) {
            load_lds16(ga + k0 + j * 32, ldsA + j * 4096);
            load_lds16(gb + k0 + j * 32, ldsB + j * 4096);
        }
        __syncthreads();
#pragma unroll
        for (int j = 0; j < 4; ++j) {
            bf16x8 a = *(const bf16x8*)&tA[j][wave * 16 + nl][kq];
#pragma unroll
            for (int t = 0; t < 4; ++t) {
                bf16x8 b = *(const bf16x8*)&tB[j][t * 16 + nl][kq];
                acc[t] = __builtin_amdgcn_mfma_f32_16x16x32_bf16(a, b, acc[t], 0, 0, 0);
            }
        }
        __syncthreads();
    }

    const int rbase = m0 + wave * 16 + quad * 4;  // C/D: row=quad*4+r, col=lane&15
#pragma unroll
    for (int t = 0; t < 4; ++t) {
        const int col = n0 + t * 16 + nl;
        const float bv = bias[col];
#pragma unroll
        for (int r = 0; r < 4; ++r) {
            const float v = (acc[t][r] + bv) * oscale;
            if (VT) {
                const int mrow = rbase + r;
                const int bb = mrow / T_, tt = mrow % T_;
                const int hh = col / HS_,  dd = col % HS_;
                ((bf16*)Y)[(((size_t)bb * H_ + hh) * HS_ + dd) * T_ + tt] = __float2bfloat16(v);
            } else if (sizeof(TOUT) == 2) {
                ((bf16*)Y)[(size_t)(rbase + r) * N + col] = __float2bfloat16(v);
            } else {
                ((float*)Y)[(size_t)(rbase + r) * N + col] = v;
            }
        }
    }
}

// Flash attention, wave-independent (no barriers). Block j's 4 waves own
// 16-query strips {j, 63-j, 64+j, 127-j} per (b,h) -> exactly 66 K-tile
// iterations per block. Computes S^T = K.Q^T via MFMA so each lane holds 4
// consecutive keys (regs) for query=nl: P packs to LDS as 4x ds_write_b64
// and reads back as 2x ds_read_b128 (A-operand). No max-subtraction
// (softmax shift-invariant, |s| small); SCALE pre-folded into U; row-sum l
// computed by an extra MFMA against B=ones (lands in C-layout = epilogue
// layout). Zero cross-lane ops in the loop.
__global__ __launch_bounds__(256) void flash_attn(
    const bf16* __restrict__ U, const bf16* __restrict__ Xb,
    const bf16* __restrict__ Vt, bf16* __restrict__ Y)
{
    __shared__ __align__(16) short lds_p[4][16][72];  // per-wave P tile, 144B rows

    const int j = blockIdx.x;                 // 0..31
    const int h = blockIdx.y, b = blockIdx.z;
    const int wave = threadIdx.x >> 6, lane = threadIdx.x & 63;
    const int nl = lane & 15, quad = lane >> 4, kq = quad * 8;

    const int s_idx = (wave == 0) ? j : (wave == 1) ? 63 - j
                    : (wave == 2) ? 64 + j : 127 - j;
    const int q0   = s_idx * 16;
    const int qt   = s_idx >> 2;              // last K-tile index
    const int tmax = s_idx & 3;               // live 16-key groups in diag tile

    const size_t xbase  = (size_t)b * T_ * C_ + (size_t)h * HS_;
    const size_t vtbase = ((size_t)(b * H_ + h)) * HS_ * T_;

    // Q fragments (B operand of S^T MFMA): lane nl holds U row q0+nl
    bf16x8 qa[2];
    {
        const bf16* qp = U + xbase + (size_t)(q0 + nl) * C_;
        qa[0] = *(const bf16x8*)(qp + kq);
        qa[1] = *(const bf16x8*)(qp + 32 + kq);
    }

    bf16x8 ones;
#pragma unroll
    for (int i = 0; i < 8; ++i) ones[i] = (short)0x3F80;  // bf16 1.0

    f32x4 o[4] = {f32x4{0,0,0,0}, f32x4{0,0,0,0}, f32x4{0,0,0,0}, f32x4{0,0,0,0}};
    f32x4 lacc = f32x4{0, 0, 0, 0};
    short* myp = &lds_p[wave][0][0];

    for (int kt = 0; kt <= qt; ++kt) {
        const bool diag = (kt == qt);

        // S^T = K.Q^T : lane (quad,nl) reg r = S[q=q0+nl][key=kt*64+16t+4quad+r]
        f32x4 s[4];
#pragma unroll
        for (int t = 0; t < 4; ++t) {
            s[t] = f32x4{0, 0, 0, 0};
            if (!diag || t <= tmax) {
                const bf16* kp = Xb + xbase + (size_t)(kt * 64 + t * 16 + nl) * C_;
                bf16x8 k0v = *(const bf16x8*)(kp + kq);
                bf16x8 k1v = *(const bf16x8*)(kp + 32 + kq);
                s[t] = __builtin_amdgcn_mfma_f32_16x16x32_bf16(k0v, qa[0], s[t], 0, 0, 0);
                s[t] = __builtin_amdgcn_mfma_f32_16x16x32_bf16(k1v, qa[1], s[t], 0, 0, 0);
            }
        }

        // p = exp(s) (SCALE pre-folded into U), pack 4 keys -> one b64 write
#pragma unroll
        for (int t = 0; t < 4; ++t) {
            unsigned lo = 0, hi = 0;
            if (!diag || t <= tmax) {
                float p[4];
#pragma unroll
                for (int r = 0; r < 4; ++r) {
                    if (diag) {
                        const int gk = kt * 64 + t * 16 + quad * 4 + r;
                        p[r] = (gk > q0 + nl) ? 0.f : __expf(s[t][r]);
                    } else {
                        p[r] = __expf(s[t][r]);
                    }
                }
                lo = (unsigned short)bf16bits(p[0]) | ((unsigned)(unsigned short)bf16bits(p[1]) << 16);
                hi = (unsigned short)bf16bits(p[2]) | ((unsigned)(unsigned short)bf16bits(p[3]) << 16);
            }
            *(uint2*)&myp[nl * 72 + t * 16 + quad * 4] = make_uint2(lo, hi);
        }

        // read back as A operand: A[m=nl][k=quad*8+j]
        bf16x8 pa0 = *(const bf16x8*)&myp[nl * 72 + kq];
        bf16x8 pa1 = *(const bf16x8*)&myp[nl * 72 + 32 + kq];

        // O += P.V ; l += P.1
#pragma unroll
        for (int t = 0; t < 4; ++t) {
            const bf16* vp = Vt + vtbase + (size_t)(t * 16 + nl) * T_ + kt * 64;
            o[t] = __builtin_amdgcn_mfma_f32_16x16x32_bf16(pa0, *(const bf16x8*)(vp + kq), o[t], 0, 0, 0);
            o[t] = __builtin_amdgcn_mfma_f32_16x16x32_bf16(pa1, *(const bf16x8*)(vp + 32 + kq), o[t], 0, 0, 0);
        }
        lacc = __builtin_amdgcn_mfma_f32_16x16x32_bf16(pa0, ones, lacc, 0, 0, 0);
        lacc = __builtin_amdgcn_mfma_f32_16x16x32_bf16(pa1, ones, lacc, 0, 0, 0);
    }

    // epilogue: O C-layout row=q0+quad*4+r, col=d=t*16+nl; l in same row layout
#pragma unroll
    for (int r = 0; r < 4; ++r) {
        const float inv_l = 1.f / lacc[r];
        const size_t yrow = xbase + (size_t)(q0 + quad * 4 + r) * C_;
#pragma unroll
        for (int t = 0; t < 4; ++t)
            Y[yrow + t * 16 + nl] = __float2bfloat16(o[t][r] * inv_l);
    }
}

extern "C" void kernel_launch(void* const* d_in, const int* in_sizes, int n_in,
                              void* d_out, int out_size, void* d_ws, size_t ws_size,
                              hipStream_t stream) {
    const float* x   = (const float*)d_in[0];
    const float* w_u = (const float*)d_in[1];
    const float* b_u = (const float*)d_in[2];
    const float* w_v = (const float*)d_in[3];
    const float* b_v = (const float*)d_in[4];
    const float* w_p = (const float*)d_in[5];
    const float* b_p = (const float*)d_in[6];
    float* out = (float*)d_out;

    char* ws = (char*)d_ws;
    const size_t slab = (size_t)XN_ * sizeof(bf16);   // 6291456
    bf16* Xb  = (bf16*)(ws);
    bf16* U   = (bf16*)(ws + slab);
    bf16* Vt  = (bf16*)(ws + 2 * slab);
    bf16* Yw  = (bf16*)(ws + 3 * slab);
    bf16* Wub = (bf16*)(ws + 4 * slab);
    bf16* Wvb = (bf16*)(ws + 4 * slab + (size_t)WN_ * 2);
    bf16* Wpb = (bf16*)(ws + 4 * slab + (size_t)WN_ * 4);

    dim3 blk(256);
    cvt_all<<<(XN_ + 3 * WN_) / 1024, blk, 0, stream>>>(x, w_u, w_v, w_p, Xb, Wub, Wvb, Wpb);

    dim3 ggrid(M_ / 64, C_ / 64);   // (64, 12)
    gemm_lds<bf16, 0><<<ggrid, blk, 0, stream>>>(Xb, Wub, b_u, U,  M_, C_, C_, SCALE_);
    gemm_lds<bf16, 1><<<ggrid, blk, 0, stream>>>(Xb, Wvb, b_v, Vt, M_, C_, C_, 1.0f);

    dim3 agrid(T_ / 64, H_, B_);    // (32, 12, 2)
    flash_attn<<<agrid, blk, 0, stream>>>(U, Xb, Vt, Yw);

    gemm_lds<float, 0><<<ggrid, blk, 0, stream>>>(Yw, Wpb, b_p, out, M_, C_, C_, 1.0f);
}

// Round 6
// 172.630 us; speedup vs baseline: 1.4518x; 1.4518x over previous
//
#include <hip/hip_runtime.h>
#include <hip/hip_bf16.h>

typedef __hip_bfloat16 bf16;
typedef short bf16x8 __attribute__((ext_vector_type(8)));
typedef short short4v __attribute__((ext_vector_type(4)));
typedef float f32x4 __attribute__((ext_vector_type(4)));

#define B_ 2
#define T_ 2048
#define C_ 768
#define H_ 12
#define HS_ 64
#define M_ (B_ * T_)              // 4096
#define XN_ (B_ * T_ * C_)        // 3145728
#define WN_ (C_ * C_)             // 589824
#define SCALE_ 0.036084391824351615f  // 1/sqrt(768)

__device__ inline short bf16bits(float f) {
    union { bf16 b; short s; } u; u.b = __float2bfloat16(f); return u.s;
}

__device__ inline void load_lds16(const void* g, void* l) {
    __builtin_amdgcn_global_load_lds(
        (const __attribute__((address_space(1))) unsigned int*)g,
        (__attribute__((address_space(3))) unsigned int*)l, 16, 0, 0);
}

// fp32 -> bf16 for x, w_u, w_v, w_p in one pass (4 elems/thread)
__global__ __launch_bounds__(256) void cvt_all(
    const float* __restrict__ x,  const float* __restrict__ wu,
    const float* __restrict__ wv, const float* __restrict__ wp,
    bf16* __restrict__ Xb,  bf16* __restrict__ Wub,
    bf16* __restrict__ Wvb, bf16* __restrict__ Wpb)
{
    const long e = (long)(blockIdx.x * 256 + threadIdx.x) * 4;
    const float* src; bf16* dst; long off;
    if (e < XN_)                { src = x;  dst = Xb;  off = e; }
    else if (e < XN_ + WN_)     { src = wu; dst = Wub; off = e - XN_; }
    else if (e < XN_ + 2*WN_)   { src = wv; dst = Wvb; off = e - XN_ - WN_; }
    else                        { src = wp; dst = Wpb; off = e - XN_ - 2L*WN_; }
    f32x4 v = *(const f32x4*)(src + off);
    short4v o;
#pragma unroll
    for (int i = 0; i < 4; ++i) o[i] = bf16bits(v[i]);
    *(short4v*)(dst + off) = o;
}

// sigma^-1 for the PV key permutation: tau bits [u|h|q1 q0|r1 r0] -> [u|q1 q0|h|r1 r0]
__device__ inline int sig_inv(int tau) {
    return (tau & 0x23) | ((tau & 0x10) >> 2) | ((tau & 0x0C) << 1);
}

// Y[m][n] = (sum_k A[m][k]*W[n][k] + bias[n]) * oscale. 128x128 tile, BK=64,
// 4 waves (2x2), 16 acc frags/wave, XOR-swizzled LDS (chunk ^ row&7).
// VT=1: scatter to Vt[b][h][d][sigma/chunk-swizzled key] for the PV pass.
template<typename TOUT, int VT>
__global__ __launch_bounds__(256) void gemm128(
    const bf16* __restrict__ A, const bf16* __restrict__ Wb,
    const float* __restrict__ bias, TOUT* __restrict__ Y,
    int M, int N, int K, float oscale)
{
    __shared__ __align__(16) short tA[128 * 64];
    __shared__ __align__(16) short tB[128 * 64];

    const int tid = threadIdx.x;
    const int w = tid >> 6, lane = tid & 63;
    const int nl = lane & 15, quad = lane >> 4;
    const int wm = w >> 1, wn = w & 1;
    const int m0 = blockIdx.x * 128, n0 = blockIdx.y * 128;

    f32x4 acc[4][4];
#pragma unroll
    for (int a = 0; a < 4; ++a)
#pragma unroll
        for (int t = 0; t < 4; ++t) acc[a][t] = f32x4{0, 0, 0, 0};

    for (int k0 = 0; k0 < K; k0 += 64) {
#pragma unroll
        for (int i = 0; i < 4; ++i) {
            const int g   = (i * 4 + w) * 64 + lane;   // chunk id 0..1023
            const int row = g >> 3, kp = g & 7;
            const int kc  = kp ^ (row & 7);            // global k-chunk (swizzle)
            load_lds16(A  + (size_t)(m0 + row) * K + k0 + kc * 8, (char*)tA + (i * 4 + w) * 1024);
            load_lds16(Wb + (size_t)(n0 + row) * K + k0 + kc * 8, (char*)tB + (i * 4 + w) * 1024);
        }
        __syncthreads();
#pragma unroll
        for (int half = 0; half < 2; ++half) {
            bf16x8 af[4], bfr[4];
#pragma unroll
            for (int a = 0; a < 4; ++a) {
                const int row = wm * 64 + a * 16 + nl;
                af[a] = *(const bf16x8*)((const char*)tA + row * 128 + (((half * 4 + quad) ^ (nl & 7)) * 16));
            }
#pragma unroll
            for (int t = 0; t < 4; ++t) {
                const int row = wn * 64 + t * 16 + nl;
                bfr[t] = *(const bf16x8*)((const char*)tB + row * 128 + (((half * 4 + quad) ^ (nl & 7)) * 16));
            }
#pragma unroll
            for (int a = 0; a < 4; ++a)
#pragma unroll
                for (int t = 0; t < 4; ++t)
                    acc[a][t] = __builtin_amdgcn_mfma_f32_16x16x32_bf16(af[a], bfr[t], acc[a][t], 0, 0, 0);
        }
        __syncthreads();
    }

#pragma unroll
    for (int a = 0; a < 4; ++a) {
#pragma unroll
        for (int t = 0; t < 4; ++t) {
            const int col = n0 + wn * 64 + t * 16 + nl;
            const float bv = bias[col];
#pragma unroll
            for (int r = 0; r < 4; ++r) {
                const int mrow = m0 + wm * 64 + a * 16 + quad * 4 + r;
                const float v = (acc[a][t][r] + bv) * oscale;
                if (VT) {
                    const int bb = mrow / T_, tt = mrow % T_;
                    const int hh = col / HS_, dd = col % HS_;
                    const int lam = sig_inv(tt & 63);
                    const int pos = (tt & ~63) + (((lam >> 3) ^ (dd & 7)) * 8) + (lam & 7);
                    ((bf16*)Y)[(((size_t)bb * H_ + hh) * HS_ + dd) * T_ + pos] = __float2bfloat16(v);
                } else if (sizeof(TOUT) == 2) {
                    ((bf16*)Y)[(size_t)mrow * N + col] = __float2bfloat16(v);
                } else {
                    ((float*)Y)[(size_t)mrow * N + col] = v;
                }
            }
        }
    }
}

// Flash attention, block-cooperative: block = 64 queries (qtile a = 31-bx,
// heavy first), 4 waves x 16 queries. K-tile (64 keys x 64 dims) gathered from
// Xb and V-tile (64 dims x 64 keys, sigma-permuted in global Vt) staged in LDS
// via global_load_lds, double-buffered, one barrier per K-tile. S^T = K.Q^T;
// exp'd C-layout regs feed the PV MFMA A-operand DIRECTLY (key permutation
// sigma absorbed into Vt layout) -> no P round-trip. No max-subtraction;
// l via ones-MFMA.
__global__ __launch_bounds__(256) void flash_attn(
    const bf16* __restrict__ U, const bf16* __restrict__ Xb,
    const bf16* __restrict__ Vt, bf16* __restrict__ Y)
{
    __shared__ __align__(16) short kbuf[2][64 * 64];   // [key][dim-chunk ^ key&7]
    __shared__ __align__(16) short vbuf[2][64 * 64];   // [d][key-pos, swizzled]

    const int a = 31 - blockIdx.x;            // qtile, heavy first
    const int h = blockIdx.y, b = blockIdx.z;
    const int w = threadIdx.x >> 6, lane = threadIdx.x & 63;
    const int nl = lane & 15, quad = lane >> 4;

    const size_t xbase = (size_t)b * T_ * C_ + (size_t)h * HS_;
    const size_t vtb   = ((size_t)(b * H_ + h)) * HS_ * T_;
    const int q0w = a * 64 + w * 16;

    bf16x8 qb0, qb1;
    {
        const bf16* qp = U + xbase + (size_t)(q0w + nl) * C_;
        qb0 = *(const bf16x8*)(qp + quad * 8);
        qb1 = *(const bf16x8*)(qp + 32 + quad * 8);
    }

    bf16x8 ones;
#pragma unroll
    for (int i = 0; i < 8; ++i) ones[i] = (short)0x3F80;

    f32x4 o[4];
#pragma unroll
    for (int g = 0; g < 4; ++g) o[g] = f32x4{0, 0, 0, 0};
    f32x4 lacc = f32x4{0, 0, 0, 0};

    // stage K/V tile kt into buffer pbuf (per-wave: 2 chunks of 1 KB each)
#define STAGE(kt_, pbuf_) do {                                                  \
        short* kb_ = kbuf[pbuf_]; short* vb_ = vbuf[pbuf_];                     \
        _Pragma("unroll")                                                       \
        for (int i_ = 0; i_ < 2; ++i_) {                                        \
            const int g_ = (w * 2 + i_) * 64 + lane;                            \
            const int rw_ = g_ >> 3, kp_ = g_ & 7;                              \
            load_lds16(Xb + xbase + (size_t)((kt_) * 64 + rw_) * C_ + ((kp_ ^ (rw_ & 7)) * 8), \
                       (char*)kb_ + (w * 2 + i_) * 1024);                       \
            load_lds16(Vt + vtb + (size_t)rw_ * T_ + (kt_) * 64 + kp_ * 8,      \
                       (char*)vb_ + (w * 2 + i_) * 1024);                       \
        }                                                                       \
    } while (0)

    STAGE(0, 0);
    int pb = 0;
    for (int kt = 0; kt <= a; ++kt) {
        __syncthreads();                       // drains stage(kt)
        if (kt < a) STAGE(kt + 1, pb ^ 1);     // prefetch overlaps compute

        const short* kb  = kbuf[pb];
        const short* vbp = vbuf[pb];
        const bool dg = (kt == a);

        // S^T = K.Q^T: lane (quad,nl) reg r = S[key=16t+4quad+r][q=q0w+nl]
        f32x4 s[4];
#pragma unroll
        for (int t = 0; t < 4; ++t) {
            s[t] = f32x4{0, 0, 0, 0};
            if (!dg || t <= w) {
                const int key = t * 16 + nl;
                bf16x8 k0 = *(const bf16x8*)((const char*)kb + key * 128 + (((0 + quad) ^ (nl & 7)) * 16));
                bf16x8 k1 = *(const bf16x8*)((const char*)kb + key * 128 + (((4 + quad) ^ (nl & 7)) * 16));
                s[t] = __builtin_amdgcn_mfma_f32_16x16x32_bf16(k0, qb0, s[t], 0, 0, 0);
                s[t] = __builtin_amdgcn_mfma_f32_16x16x32_bf16(k1, qb1, s[t], 0, 0, 0);
            }
        }

        // p = exp(s) (SCALE folded into U); pack straight into PV A-operand regs
        bf16x8 pa0, pa1;
#pragma unroll
        for (int t = 0; t < 4; ++t) {
#pragma unroll
            for (int r = 0; r < 4; ++r) {
                float p = 0.f;
                if (!dg || t <= w) {
                    p = __expf(s[t][r]);
                    if (dg && t == w) p = (4 * quad + r > nl) ? 0.f : p;
                }
                const short pb16 = bf16bits(p);
                if (t < 2) pa0[t * 4 + r] = pb16;
                else       pa1[(t - 2) * 4 + r] = pb16;
            }
        }

        // l += P.1 ; O += P.V (sigma-permuted keys match Vt layout)
        lacc = __builtin_amdgcn_mfma_f32_16x16x32_bf16(pa0, ones, lacc, 0, 0, 0);
        lacc = __builtin_amdgcn_mfma_f32_16x16x32_bf16(pa1, ones, lacc, 0, 0, 0);
#pragma unroll
        for (int g = 0; g < 4; ++g) {
            const int d = g * 16 + nl;
            bf16x8 v0 = *(const bf16x8*)((const char*)vbp + d * 128 + (((0 + quad) ^ (nl & 7)) * 16));
            bf16x8 v1 = *(const bf16x8*)((const char*)vbp + d * 128 + (((4 + quad) ^ (nl & 7)) * 16));
            o[g] = __builtin_amdgcn_mfma_f32_16x16x32_bf16(pa0, v0, o[g], 0, 0, 0);
            o[g] = __builtin_amdgcn_mfma_f32_16x16x32_bf16(pa1, v1, o[g], 0, 0, 0);
        }
        pb ^= 1;
    }
#undef STAGE

    // epilogue: row = q0w + quad*4 + r, col d = g*16 + nl (token-major Y)
#pragma unroll
    for (int r = 0; r < 4; ++r) {
        const float inv_l = 1.f / lacc[r];
        const size_t yrow = xbase + (size_t)(q0w + quad * 4 + r) * C_;
#pragma unroll
        for (int g = 0; g < 4; ++g)
            Y[yrow + g * 16 + nl] = __float2bfloat16(o[g][r] * inv_l);
    }
}

extern "C" void kernel_launch(void* const* d_in, const int* in_sizes, int n_in,
                              void* d_out, int out_size, void* d_ws, size_t ws_size,
                              hipStream_t stream) {
    const float* x   = (const float*)d_in[0];
    const float* w_u = (const float*)d_in[1];
    const float* b_u = (const float*)d_in[2];
    const float* w_v = (const float*)d_in[3];
    const float* b_v = (const float*)d_in[4];
    const float* w_p = (const float*)d_in[5];
    const float* b_p = (const float*)d_in[6];
    float* out = (float*)d_out;

    char* ws = (char*)d_ws;
    const size_t slab = (size_t)XN_ * sizeof(bf16);   // 6291456
    bf16* Xb  = (bf16*)(ws);
    bf16* U   = (bf16*)(ws + slab);
    bf16* Vt  = (bf16*)(ws + 2 * slab);
    bf16* Yw  = (bf16*)(ws + 3 * slab);
    bf16* Wub = (bf16*)(ws + 4 * slab);
    bf16* Wvb = (bf16*)(ws + 4 * slab + (size_t)WN_ * 2);
    bf16* Wpb = (bf16*)(ws + 4 * slab + (size_t)WN_ * 4);

    dim3 blk(256);
    cvt_all<<<(XN_ + 3 * WN_) / 1024, blk, 0, stream>>>(x, w_u, w_v, w_p, Xb, Wub, Wvb, Wpb);

    dim3 ggrid(M_ / 128, C_ / 128);   // (32, 6)
    gemm128<bf16, 0><<<ggrid, blk, 0, stream>>>(Xb, Wub, b_u, U,  M_, C_, C_, SCALE_);
    gemm128<bf16, 1><<<ggrid, blk, 0, stream>>>(Xb, Wvb, b_v, Vt, M_, C_, C_, 1.0f);

    dim3 agrid(T_ / 64, H_, B_);      // (32, 12, 2)
    flash_attn<<<agrid, blk, 0, stream>>>(U, Xb, Vt, Yw);

    gemm128<float, 0><<<ggrid, blk, 0, stream>>>(Yw, Wpb, b_p, out, M_, C_, C_, 1.0f);
}

// Round 7
// 170.016 us; speedup vs baseline: 1.4741x; 1.0154x over previous
//
#include <hip/hip_runtime.h>
#include <hip/hip_bf16.h>

typedef __hip_bfloat16 bf16;
typedef short bf16x8 __attribute__((ext_vector_type(8)));
typedef short short4v __attribute__((ext_vector_type(4)));
typedef float f32x4 __attribute__((ext_vector_type(4)));

#define B_ 2
#define T_ 2048
#define C_ 768
#define H_ 12
#define HS_ 64
#define M_ (B_ * T_)              // 4096
#define XN_ (B_ * T_ * C_)        // 3145728
#define WN_ (C_ * C_)             // 589824
#define SCALE_ 0.036084391824351615f  // 1/sqrt(768)

__device__ inline short bf16bits(float f) {
    union { bf16 b; short s; } u; u.b = __float2bfloat16(f); return u.s;
}

__device__ inline void load_lds16(const void* g, void* l) {
    __builtin_amdgcn_global_load_lds(
        (const __attribute__((address_space(1))) unsigned int*)g,
        (__attribute__((address_space(3))) unsigned int*)l, 16, 0, 0);
}

// fp32 -> bf16 for x, w_u, w_v, w_p in one pass (4 elems/thread)
__global__ __launch_bounds__(256) void cvt_all(
    const float* __restrict__ x,  const float* __restrict__ wu,
    const float* __restrict__ wv, const float* __restrict__ wp,
    bf16* __restrict__ Xb,  bf16* __restrict__ Wub,
    bf16* __restrict__ Wvb, bf16* __restrict__ Wpb)
{
    const long e = (long)(blockIdx.x * 256 + threadIdx.x) * 4;
    const float* src; bf16* dst; long off;
    if (e < XN_)                { src = x;  dst = Xb;  off = e; }
    else if (e < XN_ + WN_)     { src = wu; dst = Wub; off = e - XN_; }
    else if (e < XN_ + 2*WN_)   { src = wv; dst = Wvb; off = e - XN_ - WN_; }
    else                        { src = wp; dst = Wpb; off = e - XN_ - 2L*WN_; }
    f32x4 v = *(const f32x4*)(src + off);
    short4v o;
#pragma unroll
    for (int i = 0; i < 4; ++i) o[i] = bf16bits(v[i]);
    *(short4v*)(dst + off) = o;
}

// sigma^-1 for the PV key permutation: tau bits [u|h|q1 q0|r1 r0] -> [u|q1 q0|h|r1 r0]
__device__ inline int sig_inv(int tau) {
    return (tau & 0x23) | ((tau & 0x10) >> 2) | ((tau & 0x0C) << 1);
}

// Fused U/V projection. Grid (M/128, 12): by<6 -> U tile (oscale=SCALE),
// by>=6 -> V tile scattered to Vt[b][h][d][sigma/chunk-swizzled key].
// 128x128 tile, BK=64, XOR-swizzled LDS.
__global__ __launch_bounds__(256) void gemm_uv(
    const bf16* __restrict__ Xb, const bf16* __restrict__ Wu,
    const bf16* __restrict__ Wv, const float* __restrict__ bu,
    const float* __restrict__ bv, bf16* __restrict__ U, bf16* __restrict__ Vt)
{
    __shared__ __align__(16) short tA[128 * 64];
    __shared__ __align__(16) short tB[128 * 64];

    const int tid = threadIdx.x;
    const int w = tid >> 6, lane = tid & 63;
    const int nl = lane & 15, quad = lane >> 4;
    const int wm = w >> 1, wn = w & 1;
    const int m0 = blockIdx.x * 128;
    const bool isV = blockIdx.y >= 6;
    const int n0 = (isV ? blockIdx.y - 6 : blockIdx.y) * 128;
    const bf16* Wb = isV ? Wv : Wu;
    const float* bias = isV ? bv : bu;

    f32x4 acc[4][4];
#pragma unroll
    for (int a = 0; a < 4; ++a)
#pragma unroll
        for (int t = 0; t < 4; ++t) acc[a][t] = f32x4{0, 0, 0, 0};

    for (int k0 = 0; k0 < C_; k0 += 64) {
#pragma unroll
        for (int i = 0; i < 4; ++i) {
            const int g   = (i * 4 + w) * 64 + lane;   // chunk id 0..1023
            const int row = g >> 3, kp = g & 7;
            const int kc  = kp ^ (row & 7);            // global k-chunk (swizzle)
            load_lds16(Xb + (size_t)(m0 + row) * C_ + k0 + kc * 8, (char*)tA + (i * 4 + w) * 1024);
            load_lds16(Wb + (size_t)(n0 + row) * C_ + k0 + kc * 8, (char*)tB + (i * 4 + w) * 1024);
        }
        __syncthreads();
#pragma unroll
        for (int half = 0; half < 2; ++half) {
            bf16x8 af[4], bfr[4];
#pragma unroll
            for (int a = 0; a < 4; ++a) {
                const int row = wm * 64 + a * 16 + nl;
                af[a] = *(const bf16x8*)((const char*)tA + row * 128 + (((half * 4 + quad) ^ (nl & 7)) * 16));
            }
#pragma unroll
            for (int t = 0; t < 4; ++t) {
                const int row = wn * 64 + t * 16 + nl;
                bfr[t] = *(const bf16x8*)((const char*)tB + row * 128 + (((half * 4 + quad) ^ (nl & 7)) * 16));
            }
#pragma unroll
            for (int a = 0; a < 4; ++a)
#pragma unroll
                for (int t = 0; t < 4; ++t)
                    acc[a][t] = __builtin_amdgcn_mfma_f32_16x16x32_bf16(af[a], bfr[t], acc[a][t], 0, 0, 0);
        }
        __syncthreads();
    }

#pragma unroll
    for (int a = 0; a < 4; ++a) {
#pragma unroll
        for (int t = 0; t < 4; ++t) {
            const int col = n0 + wn * 64 + t * 16 + nl;
            const float bv_ = bias[col];
#pragma unroll
            for (int r = 0; r < 4; ++r) {
                const int mrow = m0 + wm * 64 + a * 16 + quad * 4 + r;
                if (isV) {
                    const float v = acc[a][t][r] + bv_;
                    const int bb = mrow / T_, tt = mrow % T_;
                    const int hh = col / HS_, dd = col % HS_;
                    const int lam = sig_inv(tt & 63);
                    const int pos = (tt & ~63) + (((lam >> 3) ^ (dd & 7)) * 8) + (lam & 7);
                    Vt[(((size_t)bb * H_ + hh) * HS_ + dd) * T_ + pos] = __float2bfloat16(v);
                } else {
                    const float v = (acc[a][t][r] + bv_) * SCALE_;
                    U[(size_t)mrow * C_ + col] = __float2bfloat16(v);
                }
            }
        }
    }
}

// proj GEMM: Y[m][n] = sum_k A[m][k]*W[n][k] + bias[n], fp32 out. 128x128 tile.
__global__ __launch_bounds__(256) void gemm_proj(
    const bf16* __restrict__ A, const bf16* __restrict__ Wb,
    const float* __restrict__ bias, float* __restrict__ Y)
{
    __shared__ __align__(16) short tA[128 * 64];
    __shared__ __align__(16) short tB[128 * 64];

    const int tid = threadIdx.x;
    const int w = tid >> 6, lane = tid & 63;
    const int nl = lane & 15, quad = lane >> 4;
    const int wm = w >> 1, wn = w & 1;
    const int m0 = blockIdx.x * 128, n0 = blockIdx.y * 128;

    f32x4 acc[4][4];
#pragma unroll
    for (int a = 0; a < 4; ++a)
#pragma unroll
        for (int t = 0; t < 4; ++t) acc[a][t] = f32x4{0, 0, 0, 0};

    for (int k0 = 0; k0 < C_; k0 += 64) {
#pragma unroll
        for (int i = 0; i < 4; ++i) {
            const int g   = (i * 4 + w) * 64 + lane;
            const int row = g >> 3, kp = g & 7;
            const int kc  = kp ^ (row & 7);
            load_lds16(A  + (size_t)(m0 + row) * C_ + k0 + kc * 8, (char*)tA + (i * 4 + w) * 1024);
            load_lds16(Wb + (size_t)(n0 + row) * C_ + k0 + kc * 8, (char*)tB + (i * 4 + w) * 1024);
        }
        __syncthreads();
#pragma unroll
        for (int half = 0; half < 2; ++half) {
            bf16x8 af[4], bfr[4];
#pragma unroll
            for (int a = 0; a < 4; ++a) {
                const int row = wm * 64 + a * 16 + nl;
                af[a] = *(const bf16x8*)((const char*)tA + row * 128 + (((half * 4 + quad) ^ (nl & 7)) * 16));
            }
#pragma unroll
            for (int t = 0; t < 4; ++t) {
                const int row = wn * 64 + t * 16 + nl;
                bfr[t] = *(const bf16x8*)((const char*)tB + row * 128 + (((half * 4 + quad) ^ (nl & 7)) * 16));
            }
#pragma unroll
            for (int a = 0; a < 4; ++a)
#pragma unroll
                for (int t = 0; t < 4; ++t)
                    acc[a][t] = __builtin_amdgcn_mfma_f32_16x16x32_bf16(af[a], bfr[t], acc[a][t], 0, 0, 0);
        }
        __syncthreads();
    }

#pragma unroll
    for (int a = 0; a < 4; ++a) {
#pragma unroll
        for (int t = 0; t < 4; ++t) {
            const int col = n0 + wn * 64 + t * 16 + nl;
            const float bv = bias[col];
#pragma unroll
            for (int r = 0; r < 4; ++r) {
                const int mrow = m0 + wm * 64 + a * 16 + quad * 4 + r;
                Y[(size_t)mrow * C_ + col] = acc[a][t][r] + bv;
            }
        }
    }
}

// Flash attention, block = 128 queries (qtile-pair a2 = 15-bx, heavy first),
// 8 waves x 16 queries, 512 threads. K-tile + sigma-permuted V-tile staged
// once per block in LDS (global_load_lds, double-buffered). S^T = K.Q^T;
// exp'd C-layout regs feed PV A-operand directly. l via ones-MFMA.
// Waves 0-3 (lower 64 q) skip compute in the final iteration.
__global__ __launch_bounds__(512) void flash_attn(
    const bf16* __restrict__ U, const bf16* __restrict__ Xb,
    const bf16* __restrict__ Vt, bf16* __restrict__ Y)
{
    __shared__ __align__(16) short kbuf[2][64 * 64];   // [key][dim-chunk ^ key&7]
    __shared__ __align__(16) short vbuf[2][64 * 64];   // [d][key-pos, swizzled]

    const int a2 = 15 - blockIdx.x;           // qtile pair, heavy first
    const int h = blockIdx.y, b = blockIdx.z;
    const int tid = threadIdx.x;
    const int w = tid >> 6, lane = tid & 63;
    const int nl = lane & 15, quad = lane >> 4;

    const size_t xbase = (size_t)b * T_ * C_ + (size_t)h * HS_;
    const size_t vtb   = ((size_t)(b * H_ + h)) * HS_ * T_;
    const int q0w = a2 * 128 + w * 16;
    const int ktmax = 2 * a2 + 1;
    const int full  = 2 * a2 + (w >> 2);      // this wave's diagonal tile
    const int tmax  = w & 3;

    bf16x8 qb0, qb1;
    {
        const bf16* qp = U + xbase + (size_t)(q0w + nl) * C_;
        qb0 = *(const bf16x8*)(qp + quad * 8);
        qb1 = *(const bf16x8*)(qp + 32 + quad * 8);
    }

    bf16x8 ones;
#pragma unroll
    for (int i = 0; i < 8; ++i) ones[i] = (short)0x3F80;

    f32x4 o[4];
#pragma unroll
    for (int g = 0; g < 4; ++g) o[g] = f32x4{0, 0, 0, 0};
    f32x4 lacc = f32x4{0, 0, 0, 0};

    const int srw = tid >> 3, skp = tid & 7;  // staging: row, 8-elem chunk
    auto stage = [&](int kt_, int pbuf_) {
        load_lds16(Xb + xbase + (size_t)(kt_ * 64 + srw) * C_ + ((skp ^ (srw & 7)) * 8),
                   (char*)kbuf[pbuf_] + w * 1024);
        load_lds16(Vt + vtb + (size_t)srw * T_ + kt_ * 64 + skp * 8,
                   (char*)vbuf[pbuf_] + w * 1024);
    };

    stage(0, 0);
    int pb = 0;
    for (int kt = 0; kt <= ktmax; ++kt) {
        __syncthreads();                       // drains stage(kt)
        if (kt < ktmax) stage(kt + 1, pb ^ 1); // prefetch overlaps compute

        if (kt <= full) {
            const short* kb  = kbuf[pb];
            const short* vbp = vbuf[pb];
            const bool dg = (kt == full);

            // S^T = K.Q^T: lane (quad,nl) reg r = S[key=16t+4quad+r][q=q0w+nl]
            f32x4 s[4];
#pragma unroll
            for (int t = 0; t < 4; ++t) {
                s[t] = f32x4{0, 0, 0, 0};
                if (!dg || t <= tmax) {
                    const int key = t * 16 + nl;
                    bf16x8 k0 = *(const bf16x8*)((const char*)kb + key * 128 + (((0 + quad) ^ (nl & 7)) * 16));
                    bf16x8 k1 = *(const bf16x8*)((const char*)kb + key * 128 + (((4 + quad) ^ (nl & 7)) * 16));
                    s[t] = __builtin_amdgcn_mfma_f32_16x16x32_bf16(k0, qb0, s[t], 0, 0, 0);
                    s[t] = __builtin_amdgcn_mfma_f32_16x16x32_bf16(k1, qb1, s[t], 0, 0, 0);
                }
            }

            // p = exp(s) (SCALE folded into U); pack into PV A-operand regs
            bf16x8 pa0, pa1;
#pragma unroll
            for (int t = 0; t < 4; ++t) {
#pragma unroll
                for (int r = 0; r < 4; ++r) {
                    float p = 0.f;
                    if (!dg || t <= tmax) {
                        p = __expf(s[t][r]);
                        if (dg && t == tmax) p = (4 * quad + r > nl) ? 0.f : p;
                    }
                    const short pb16 = bf16bits(p);
                    if (t < 2) pa0[t * 4 + r] = pb16;
                    else       pa1[(t - 2) * 4 + r] = pb16;
                }
            }

            // l += P.1 ; O += P.V (sigma-permuted keys match Vt layout)
            lacc = __builtin_amdgcn_mfma_f32_16x16x32_bf16(pa0, ones, lacc, 0, 0, 0);
            lacc = __builtin_amdgcn_mfma_f32_16x16x32_bf16(pa1, ones, lacc, 0, 0, 0);
#pragma unroll
            for (int g = 0; g < 4; ++g) {
                const int d = g * 16 + nl;
                bf16x8 v0 = *(const bf16x8*)((const char*)vbp + d * 128 + (((0 + quad) ^ (nl & 7)) * 16));
                bf16x8 v1 = *(const bf16x8*)((const char*)vbp + d * 128 + (((4 + quad) ^ (nl & 7)) * 16));
                o[g] = __builtin_amdgcn_mfma_f32_16x16x32_bf16(pa0, v0, o[g], 0, 0, 0);
                o[g] = __builtin_amdgcn_mfma_f32_16x16x32_bf16(pa1, v1, o[g], 0, 0, 0);
            }
        }
        pb ^= 1;
    }

    // epilogue: row = q0w + quad*4 + r, col d = g*16 + nl (token-major Y)
#pragma unroll
    for (int r = 0; r < 4; ++r) {
        const float inv_l = 1.f / lacc[r];
        const size_t yrow = xbase + (size_t)(q0w + quad * 4 + r) * C_;
#pragma unroll
        for (int g = 0; g < 4; ++g)
            Y[yrow + g * 16 + nl] = __float2bfloat16(o[g][r] * inv_l);
    }
}

extern "C" void kernel_launch(void* const* d_in, const int* in_sizes, int n_in,
                              void* d_out, int out_size, void* d_ws, size_t ws_size,
                              hipStream_t stream) {
    const float* x   = (const float*)d_in[0];
    const float* w_u = (const float*)d_in[1];
    const float* b_u = (const float*)d_in[2];
    const float* w_v = (const float*)d_in[3];
    const float* b_v = (const float*)d_in[4];
    const float* w_p = (const float*)d_in[5];
    const float* b_p = (const float*)d_in[6];
    float* out = (float*)d_out;

    char* ws = (char*)d_ws;
    const size_t slab = (size_t)XN_ * sizeof(bf16);   // 6291456
    bf16* Xb  = (bf16*)(ws);
    bf16* U   = (bf16*)(ws + slab);
    bf16* Vt  = (bf16*)(ws + 2 * slab);
    bf16* Yw  = (bf16*)(ws + 3 * slab);
    bf16* Wub = (bf16*)(ws + 4 * slab);
    bf16* Wvb = (bf16*)(ws + 4 * slab + (size_t)WN_ * 2);
    bf16* Wpb = (bf16*)(ws + 4 * slab + (size_t)WN_ * 4);

    dim3 blk(256);
    cvt_all<<<(XN_ + 3 * WN_) / 1024, blk, 0, stream>>>(x, w_u, w_v, w_p, Xb, Wub, Wvb, Wpb);

    gemm_uv<<<dim3(M_ / 128, 12), blk, 0, stream>>>(Xb, Wub, Wvb, b_u, b_v, U, Vt);

    flash_attn<<<dim3(T_ / 128, H_, B_), dim3(512), 0, stream>>>(U, Xb, Vt, Yw);

    gemm_proj<<<dim3(M_ / 128, C_ / 128), blk, 0, stream>>>(Yw, Wpb, b_p, out);
}

// Round 8
// 149.940 us; speedup vs baseline: 1.6715x; 1.1339x over previous
//
#include <hip/hip_runtime.h>
#include <hip/hip_bf16.h>

typedef __hip_bfloat16 bf16;
typedef short bf16x8 __attribute__((ext_vector_type(8)));
typedef short short4v __attribute__((ext_vector_type(4)));
typedef float f32x4 __attribute__((ext_vector_type(4)));

#define B_ 2
#define T_ 2048
#define C_ 768
#define H_ 12
#define HS_ 64
#define M_ (B_ * T_)              // 4096
#define XN_ (B_ * T_ * C_)        // 3145728
#define WN_ (C_ * C_)             // 589824
#define SCALE_ 0.036084391824351615f  // 1/sqrt(768)

__device__ inline short bf16bits(float f) {
    union { bf16 b; short s; } u; u.b = __float2bfloat16(f); return u.s;
}

__device__ inline void load_lds16(const void* g, void* l) {
    __builtin_amdgcn_global_load_lds(
        (const __attribute__((address_space(1))) unsigned int*)g,
        (__attribute__((address_space(3))) unsigned int*)l, 16, 0, 0);
}

// fp32 -> bf16 for x, w_u, w_v, w_p in one pass (4 elems/thread)
__global__ __launch_bounds__(256) void cvt_all(
    const float* __restrict__ x,  const float* __restrict__ wu,
    const float* __restrict__ wv, const float* __restrict__ wp,
    bf16* __restrict__ Xb,  bf16* __restrict__ Wub,
    bf16* __restrict__ Wvb, bf16* __restrict__ Wpb)
{
    const long e = (long)(blockIdx.x * 256 + threadIdx.x) * 4;
    const float* src; bf16* dst; long off;
    if (e < XN_)                { src = x;  dst = Xb;  off = e; }
    else if (e < XN_ + WN_)     { src = wu; dst = Wub; off = e - XN_; }
    else if (e < XN_ + 2*WN_)   { src = wv; dst = Wvb; off = e - XN_ - WN_; }
    else                        { src = wp; dst = Wpb; off = e - XN_ - 2L*WN_; }
    f32x4 v = *(const f32x4*)(src + off);
    short4v o;
#pragma unroll
    for (int i = 0; i < 4; ++i) o[i] = bf16bits(v[i]);
    *(short4v*)(dst + off) = o;
}

// sigma^-1 for the PV key permutation: tau bits [u|h|q1 q0|r1 r0] -> [u|q1 q0|h|r1 r0]
__device__ inline int sig_inv(int tau) {
    return (tau & 0x23) | ((tau & 0x10) >> 2) | ((tau & 0x0C) << 1);
}

// Fused U/V projection, 64x128 tile, grid (M/64, 12) = 768 blocks (3/CU).
// by<6 -> U tile (oscale=SCALE); by>=6 -> V scattered to sigma/swizzled Vt.
// Wave w: cols w*32..w*32+31 (2 frags) x rows 0..63 (4 frags).
__global__ __launch_bounds__(256) void gemm_uv(
    const bf16* __restrict__ Xb, const bf16* __restrict__ Wu,
    const bf16* __restrict__ Wv, const float* __restrict__ bu,
    const float* __restrict__ bv, bf16* __restrict__ U, bf16* __restrict__ Vt)
{
    __shared__ __align__(16) short tA[64 * 64];    // 8 KB
    __shared__ __align__(16) short tB[128 * 64];   // 16 KB

    const int tid = threadIdx.x;
    const int w = tid >> 6, lane = tid & 63;
    const int nl = lane & 15, quad = lane >> 4;
    const int m0 = blockIdx.x * 64;
    const bool isV = blockIdx.y >= 6;
    const int n0 = (isV ? blockIdx.y - 6 : blockIdx.y) * 128;
    const bf16* Wb = isV ? Wv : Wu;
    const float* bias = isV ? bv : bu;

    f32x4 acc[4][2];
#pragma unroll
    for (int a = 0; a < 4; ++a)
#pragma unroll
        for (int t = 0; t < 2; ++t) acc[a][t] = f32x4{0, 0, 0, 0};

    for (int k0 = 0; k0 < C_; k0 += 64) {
#pragma unroll
        for (int i = 0; i < 2; ++i) {           // A tile: 512 chunks
            const int g = i * 256 + tid;
            const int row = g >> 3, kp = g & 7;
            load_lds16(Xb + (size_t)(m0 + row) * C_ + k0 + (kp ^ (row & 7)) * 8,
                       (char*)tA + g * 16);
        }
#pragma unroll
        for (int i = 0; i < 4; ++i) {           // B tile: 1024 chunks
            const int g = i * 256 + tid;
            const int row = g >> 3, kp = g & 7;
            load_lds16(Wb + (size_t)(n0 + row) * C_ + k0 + (kp ^ (row & 7)) * 8,
                       (char*)tB + g * 16);
        }
        __syncthreads();
#pragma unroll
        for (int half = 0; half < 2; ++half) {
            bf16x8 af[4], bfr[2];
#pragma unroll
            for (int a = 0; a < 4; ++a) {
                const int row = a * 16 + nl;
                af[a] = *(const bf16x8*)((const char*)tA + row * 128 + (((half * 4 + quad) ^ (nl & 7)) * 16));
            }
#pragma unroll
            for (int t = 0; t < 2; ++t) {
                const int row = w * 32 + t * 16 + nl;
                bfr[t] = *(const bf16x8*)((const char*)tB + row * 128 + (((half * 4 + quad) ^ (nl & 7)) * 16));
            }
#pragma unroll
            for (int a = 0; a < 4; ++a)
#pragma unroll
                for (int t = 0; t < 2; ++t)
                    acc[a][t] = __builtin_amdgcn_mfma_f32_16x16x32_bf16(af[a], bfr[t], acc[a][t], 0, 0, 0);
        }
        __syncthreads();
    }

#pragma unroll
    for (int a = 0; a < 4; ++a) {
#pragma unroll
        for (int t = 0; t < 2; ++t) {
            const int col = n0 + w * 32 + t * 16 + nl;
            const float bv_ = bias[col];
#pragma unroll
            for (int r = 0; r < 4; ++r) {
                const int mrow = m0 + a * 16 + quad * 4 + r;
                if (isV) {
                    const float v = acc[a][t][r] + bv_;
                    const int bb = mrow / T_, tt = mrow % T_;
                    const int hh = col / HS_, dd = col % HS_;
                    const int lam = sig_inv(tt & 63);
                    const int pos = (tt & ~63) + (((lam >> 3) ^ (dd & 7)) * 8) + (lam & 7);
                    Vt[(((size_t)bb * H_ + hh) * HS_ + dd) * T_ + pos] = __float2bfloat16(v);
                } else {
                    const float v = (acc[a][t][r] + bv_) * SCALE_;
                    U[(size_t)mrow * C_ + col] = __float2bfloat16(v);
                }
            }
        }
    }
}

// proj GEMM: 64x64 tile, grid (M/64, C/64) = (64,12) = 768 blocks (3/CU).
// Wave w: rows w*16..w*16+15 x all 64 cols.
__global__ __launch_bounds__(256) void gemm_proj(
    const bf16* __restrict__ A, const bf16* __restrict__ Wb,
    const float* __restrict__ bias, float* __restrict__ Y)
{
    __shared__ __align__(16) short tA[64 * 64];
    __shared__ __align__(16) short tB[64 * 64];

    const int tid = threadIdx.x;
    const int w = tid >> 6, lane = tid & 63;
    const int nl = lane & 15, quad = lane >> 4;
    const int m0 = blockIdx.x * 64, n0 = blockIdx.y * 64;

    f32x4 acc[4];
#pragma unroll
    for (int t = 0; t < 4; ++t) acc[t] = f32x4{0, 0, 0, 0};

    for (int k0 = 0; k0 < C_; k0 += 64) {
#pragma unroll
        for (int i = 0; i < 2; ++i) {
            const int g = i * 256 + tid;
            const int row = g >> 3, kp = g & 7;
            const int kc = (kp ^ (row & 7)) * 8;
            load_lds16(A  + (size_t)(m0 + row) * C_ + k0 + kc, (char*)tA + g * 16);
            load_lds16(Wb + (size_t)(n0 + row) * C_ + k0 + kc, (char*)tB + g * 16);
        }
        __syncthreads();
#pragma unroll
        for (int half = 0; half < 2; ++half) {
            const int row = w * 16 + nl;
            bf16x8 af = *(const bf16x8*)((const char*)tA + row * 128 + (((half * 4 + quad) ^ (nl & 7)) * 16));
#pragma unroll
            for (int t = 0; t < 4; ++t) {
                const int brow = t * 16 + nl;
                bf16x8 bfr = *(const bf16x8*)((const char*)tB + brow * 128 + (((half * 4 + quad) ^ (nl & 7)) * 16));
                acc[t] = __builtin_amdgcn_mfma_f32_16x16x32_bf16(af, bfr, acc[t], 0, 0, 0);
            }
        }
        __syncthreads();
    }

#pragma unroll
    for (int t = 0; t < 4; ++t) {
        const int col = n0 + t * 16 + nl;
        const float bv = bias[col];
#pragma unroll
        for (int r = 0; r < 4; ++r) {
            const int mrow = m0 + w * 16 + quad * 4 + r;
            Y[(size_t)mrow * C_ + col] = acc[t][r] + bv;
        }
    }
}

// Flash partial: block = (64-query tile a, key-chunk c of <=8 K-tiles).
// Since there is no max-subtraction, (O,l) partials over disjoint key ranges
// are purely ADDITIVE -> key dimension parallelized across blocks, combined
// in a second pass. 80 chunks per (b,h), grid 1920 blocks (heavy first),
// 256 threads, 32 KB LDS -> 5 resident blocks/CU to hide barrier drains.
__global__ __launch_bounds__(256) void flash_part(
    const bf16* __restrict__ U, const bf16* __restrict__ Xb,
    const bf16* __restrict__ Vt, float* __restrict__ Part)
{
    __shared__ __align__(16) short kbuf[2][64 * 64];
    __shared__ __align__(16) short vbuf[2][64 * 64];

    const int i = 79 - blockIdx.x;            // heavy chunks first
    int a, c;
    if (i < 8)       { a = i;                c = 0; }
    else if (i < 24) { a = 8  + (i - 8)  / 2; c = (i - 8)  % 2; }
    else if (i < 48) { a = 16 + (i - 24) / 3; c = (i - 24) % 3; }
    else             { a = 24 + (i - 48) / 4; c = (i - 48) % 4; }
    const int kt0 = c * 8, kt1 = min(c * 8 + 7, a);

    const int h = blockIdx.y, b = blockIdx.z;
    const int w = threadIdx.x >> 6, lane = threadIdx.x & 63;
    const int nl = lane & 15, quad = lane >> 4;

    const size_t xbase = (size_t)b * T_ * C_ + (size_t)h * HS_;
    const size_t vtb   = ((size_t)(b * H_ + h)) * HS_ * T_;
    const int q0w = a * 64 + w * 16;

    bf16x8 qb0, qb1;
    {
        const bf16* qp = U + xbase + (size_t)(q0w + nl) * C_;
        qb0 = *(const bf16x8*)(qp + quad * 8);
        qb1 = *(const bf16x8*)(qp + 32 + quad * 8);
    }

    bf16x8 ones;
#pragma unroll
    for (int k = 0; k < 8; ++k) ones[k] = (short)0x3F80;

    f32x4 o[4];
#pragma unroll
    for (int g = 0; g < 4; ++g) o[g] = f32x4{0, 0, 0, 0};
    f32x4 lacc = f32x4{0, 0, 0, 0};

    auto stage = [&](int kt_, int pbuf_) {
        short* kb_ = kbuf[pbuf_]; short* vb_ = vbuf[pbuf_];
#pragma unroll
        for (int i_ = 0; i_ < 2; ++i_) {
            const int g_ = (w * 2 + i_) * 64 + lane;
            const int rw_ = g_ >> 3, kp_ = g_ & 7;
            load_lds16(Xb + xbase + (size_t)(kt_ * 64 + rw_) * C_ + ((kp_ ^ (rw_ & 7)) * 8),
                       (char*)kb_ + (w * 2 + i_) * 1024);
            load_lds16(Vt + vtb + (size_t)rw_ * T_ + kt_ * 64 + kp_ * 8,
                       (char*)vb_ + (w * 2 + i_) * 1024);
        }
    };

    stage(kt0, 0);
    int pb = 0;
    for (int kt = kt0; kt <= kt1; ++kt) {
        __syncthreads();                       // drains stage(kt)
        if (kt < kt1) stage(kt + 1, pb ^ 1);   // prefetch overlaps compute

        const short* kb  = kbuf[pb];
        const short* vbp = vbuf[pb];
        const bool dg = (kt == a);             // diagonal tile (last chunk only)

        // S^T = K.Q^T: lane (quad,nl) reg r = S[key=16t+4quad+r][q=q0w+nl]
        f32x4 s[4];
#pragma unroll
        for (int t = 0; t < 4; ++t) {
            s[t] = f32x4{0, 0, 0, 0};
            if (!dg || t <= w) {
                const int key = t * 16 + nl;
                bf16x8 k0 = *(const bf16x8*)((const char*)kb + key * 128 + (((0 + quad) ^ (nl & 7)) * 16));
                bf16x8 k1 = *(const bf16x8*)((const char*)kb + key * 128 + (((4 + quad) ^ (nl & 7)) * 16));
                s[t] = __builtin_amdgcn_mfma_f32_16x16x32_bf16(k0, qb0, s[t], 0, 0, 0);
                s[t] = __builtin_amdgcn_mfma_f32_16x16x32_bf16(k1, qb1, s[t], 0, 0, 0);
            }
        }

        // p = exp(s) (SCALE folded into U); pack into PV A-operand regs
        bf16x8 pa0, pa1;
#pragma unroll
        for (int t = 0; t < 4; ++t) {
#pragma unroll
            for (int r = 0; r < 4; ++r) {
                float p = 0.f;
                if (!dg || t <= w) {
                    p = __expf(s[t][r]);
                    if (dg && t == w) p = (4 * quad + r > nl) ? 0.f : p;
                }
                const short pb16 = bf16bits(p);
                if (t < 2) pa0[t * 4 + r] = pb16;
                else       pa1[(t - 2) * 4 + r] = pb16;
            }
        }

        // l += P.1 ; O += P.V (sigma-permuted keys match Vt layout)
        lacc = __builtin_amdgcn_mfma_f32_16x16x32_bf16(pa0, ones, lacc, 0, 0, 0);
        lacc = __builtin_amdgcn_mfma_f32_16x16x32_bf16(pa1, ones, lacc, 0, 0, 0);
#pragma unroll
        for (int g = 0; g < 4; ++g) {
            const int d = g * 16 + nl;
            bf16x8 v0 = *(const bf16x8*)((const char*)vbp + d * 128 + (((0 + quad) ^ (nl & 7)) * 16));
            bf16x8 v1 = *(const bf16x8*)((const char*)vbp + d * 128 + (((4 + quad) ^ (nl & 7)) * 16));
            o[g] = __builtin_amdgcn_mfma_f32_16x16x32_bf16(pa0, v0, o[g], 0, 0, 0);
            o[g] = __builtin_amdgcn_mfma_f32_16x16x32_bf16(pa1, v1, o[g], 0, 0, 0);
        }
        pb ^= 1;
    }

    // write fp32 partial: slot = [O 64x64 | l 64]
    float* slot = Part + (size_t)((b * H_ + h) * 80 + i) * 4160;
#pragma unroll
    for (int g = 0; g < 4; ++g)
#pragma unroll
        for (int r = 0; r < 4; ++r)
            slot[(w * 16 + quad * 4 + r) * 64 + g * 16 + nl] = o[g][r];
    if (nl == 0) {
#pragma unroll
        for (int r = 0; r < 4; ++r)
            slot[4096 + w * 16 + quad * 4 + r] = lacc[r];
    }
}

// Combine partials: grid (32, 12, 2); block sums <=4 chunks for one
// (b,h,64-q tile), divides by l, writes bf16 Yw token-major.
__global__ __launch_bounds__(256) void combine(
    const float* __restrict__ Part, bf16* __restrict__ Yw)
{
    const int a = blockIdx.x, h = blockIdx.y, b = blockIdx.z;
    const int nch = (a >> 3) + 1;
    const int base = (a < 8)  ? a
                   : (a < 16) ? 8  + (a - 8)  * 2
                   : (a < 24) ? 24 + (a - 16) * 3
                   :            48 + (a - 24) * 4;
    const int tid = threadIdx.x;
    const int q = tid >> 2, d0 = (tid & 3) * 16;
    const float* s0 = Part + (size_t)((b * H_ + h) * 80 + base) * 4160;

    f32x4 acc[4] = {f32x4{0,0,0,0}, f32x4{0,0,0,0}, f32x4{0,0,0,0}, f32x4{0,0,0,0}};
    float l = 0.f;
    for (int cc = 0; cc < nch; ++cc) {
        const float* sp = s0 + (size_t)cc * 4160;
#pragma unroll
        for (int u = 0; u < 4; ++u) acc[u] += *(const f32x4*)(sp + q * 64 + d0 + u * 4);
        l += sp[4096 + q];
    }
    const float inv = 1.f / l;
    bf16* yp = Yw + ((size_t)(b * T_ + a * 64 + q)) * C_ + h * HS_ + d0;
#pragma unroll
    for (int u = 0; u < 4; ++u) {
        short4v ov;
#pragma unroll
        for (int k = 0; k < 4; ++k) ov[k] = bf16bits(acc[u][k] * inv);
        *(short4v*)(yp + u * 4) = ov;
    }
}

extern "C" void kernel_launch(void* const* d_in, const int* in_sizes, int n_in,
                              void* d_out, int out_size, void* d_ws, size_t ws_size,
                              hipStream_t stream) {
    const float* x   = (const float*)d_in[0];
    const float* w_u = (const float*)d_in[1];
    const float* b_u = (const float*)d_in[2];
    const float* w_v = (const float*)d_in[3];
    const float* b_v = (const float*)d_in[4];
    const float* w_p = (const float*)d_in[5];
    const float* b_p = (const float*)d_in[6];
    float* out = (float*)d_out;

    char* ws = (char*)d_ws;
    const size_t slab = (size_t)XN_ * sizeof(bf16);   // 6291456
    bf16* Xb   = (bf16*)(ws);
    bf16* U    = (bf16*)(ws + slab);
    bf16* Vt   = (bf16*)(ws + 2 * slab);
    bf16* Yw   = (bf16*)(ws + 3 * slab);
    bf16* Wub  = (bf16*)(ws + 4 * slab);
    bf16* Wvb  = (bf16*)(ws + 4 * slab + (size_t)WN_ * 2);
    bf16* Wpb  = (bf16*)(ws + 4 * slab + (size_t)WN_ * 4);
    float* Prt = (float*)(ws + (size_t)32 * 1024 * 1024);   // 24*80*4160*4 ~ 32 MB

    dim3 blk(256);
    cvt_all<<<(XN_ + 3 * WN_) / 1024, blk, 0, stream>>>(x, w_u, w_v, w_p, Xb, Wub, Wvb, Wpb);

    gemm_uv<<<dim3(M_ / 64, 12), blk, 0, stream>>>(Xb, Wub, Wvb, b_u, b_v, U, Vt);

    flash_part<<<dim3(80, H_, B_), blk, 0, stream>>>(U, Xb, Vt, Prt);
    combine<<<dim3(32, H_, B_), blk, 0, stream>>>(Prt, Yw);

    gemm_proj<<<dim3(M_ / 64, C_ / 64), blk, 0, stream>>>(Yw, Wpb, b_p, out);
}